// Round 8
// baseline (102.307 us; speedup 1.0000x reference)
//
#include <hip/hip_runtime.h>

// Point-splat renderer, round 8: fused passes with DOUBLE-BUFFERED masks.
//
// winner[pix] = max point index (memory-side atomicMax, ~27 G/s measured).
// Descending-index chunk passes. Pass k: (a) project chunk [b[k+1],b[k})
// skipping pixels whose bit is set in mask_read, (b) build mask_write with
// bit p = (winner[p] >= b[k+1]) for the NEXT pass.
//
// Correctness invariants:
//  - mask a pass READS was built entirely in the previous dispatch (stream
//    order = full barrier + device-scope release) -> no poison reads (the
//    round-7 bug), no partially-built masks.
//  - read- and write-masks are disjoint buffers -> no mid-pass overwrite of
//    a stronger certificate with a weaker one.
//  - build reads winner concurrently with same-pass atomics: any bit set is
//    a true "winner >= b[k+1]" fact (monotone), which beats every index of
//    pass k+1; stale/missed updates only yield missing bits = extra atomics.
//  - build runs AFTER this thread's projection slice, so the next mask
//    captures most of this pass's own coverage (indices >= b[k+1]).
//
// Dispatches: fill + 8 proj + paint = 10 (R6: 15; ~2.2 us/dispatch measured).
//
// Inputs: d_in[0] positions (N*3 f32), d_in[1] colors (N*3 f32),
//         d_in[2] camera_pose (16 f32), d_in[3] intrinsics (9 f32),
//         d_in[4] H (1 int), d_in[5] W (1 int)
// Output: (1,3,H,W) f32 flat.

__global__ void fill_ff_kernel(uint4* __restrict__ p, int n4) {
    int i = blockIdx.x * blockDim.x + threadIdx.x;
    uint4 v = make_uint4(0xFFFFFFFFu, 0xFFFFFFFFu, 0xFFFFFFFFu, 0xFFFFFFFFu);
    for (; i < n4; i += gridDim.x * blockDim.x) p[i] = v;
}

__global__ void proj_kernel(const float* __restrict__ pos,
                            const float* __restrict__ pose,
                            const float* __restrict__ intr,
                            const int* __restrict__ Hp,
                            const int* __restrict__ Wp,
                            int* __restrict__ winner,
                            const unsigned* __restrict__ mask_r,
                            unsigned* __restrict__ mask_w,
                            int use_mask, int build,
                            int start, int end, int HW) {
    int tid = blockIdx.x * blockDim.x + threadIdx.x;
    int nthreads = gridDim.x * blockDim.x;

    // ---- projection over this chunk (grid-stride) ----
    float r00 = pose[0], r01 = pose[1], r02 = pose[2],  t0 = pose[3];
    float r10 = pose[4], r11 = pose[5], r12 = pose[6],  t1 = pose[7];
    float r20 = pose[8], r21 = pose[9], r22 = pose[10], t2 = pose[11];
    float fx = intr[0], cx = intr[2];
    float fy = intr[4], cy = intr[5];
    int W = *Wp, H = *Hp;

    for (int i = start + tid; i < end; i += nthreads) {
        float px = pos[3 * i + 0];
        float py = pos[3 * i + 1];
        float pz = pos[3 * i + 2];

        float x = r00 * px + r01 * py + r02 * pz + t0;
        float y = r10 * px + r11 * py + r12 * pz + t1;
        float z = r20 * px + r21 * py + r22 * pz + t2;

        float u = fx * x / z + cx;
        float v = fy * y / z + cy;

        int xi = (int)u;   // trunc toward zero == numpy astype(int32)
        int yi = (int)v;

        if (xi >= 0 && xi < W && yi >= 0 && yi < H) {
            int pix = yi * W + xi;
            if (use_mask && ((mask_r[pix >> 5] >> (pix & 31)) & 1u)) continue;
            atomicMax(&winner[pix], i);
        }
    }

    // ---- build next pass's mask: bit p = (winner[p] >= start) ----
    if (build) {
        for (int p0 = tid; p0 < HW; p0 += nthreads) {
            bool covered = winner[p0] >= start;
            unsigned long long b = __ballot(covered);
            if ((threadIdx.x & 63) == 0) {
                int base = p0 >> 5;            // p0 is 64-aligned for lane 0
                mask_w[base]     = (unsigned)b;
                mask_w[base + 1] = (unsigned)(b >> 32);
            }
        }
    }
}

__global__ void paint_kernel(const int* __restrict__ winner,
                             const float* __restrict__ colors,
                             float* __restrict__ out,
                             int HW) {
    int p = blockIdx.x * blockDim.x + threadIdx.x;
    if (p >= HW) return;

    int w = winner[p];
    float r = 0.0f, g = 0.0f, b = 0.0f;
    if (w >= 0) {
        r = colors[3 * w + 0];
        g = colors[3 * w + 1];
        b = colors[3 * w + 2];
        r = fminf(fmaxf(r, 0.0f), 1.0f);
        g = fminf(fmaxf(g, 0.0f), 1.0f);
        b = fminf(fmaxf(b, 0.0f), 1.0f);
    }
    out[p] = r;
    out[HW + p] = g;
    out[2 * HW + p] = b;
}

extern "C" void kernel_launch(void* const* d_in, const int* in_sizes, int n_in,
                              void* d_out, int out_size, void* d_ws, size_t ws_size,
                              hipStream_t stream) {
    const float* positions = (const float*)d_in[0];
    const float* colors    = (const float*)d_in[1];
    const float* pose      = (const float*)d_in[2];
    const float* intr      = (const float*)d_in[3];
    const int*   Hp        = (const int*)d_in[4];
    const int*   Wp        = (const int*)d_in[5];
    float* out = (float*)d_out;

    int n  = in_sizes[0] / 3;       // number of points
    int HW = out_size / 3;          // H*W pixels

    int* winner = (int*)d_ws;
    int maskWords = HW / 32;
    unsigned* maskA = (unsigned*)(winner + HW);
    unsigned* maskB = maskA + maskWords;
    size_t need = (size_t)HW * sizeof(int) + 2ull * maskWords * sizeof(unsigned);

    const int block = 256;

    if (ws_size < need || n < 4096 || (HW & 63)) {
        // Fallback: memset winner, single full atomic pass, no mask.
        hipMemsetAsync(winner, 0xFF, (size_t)HW * sizeof(int), stream);
        int grid = (n + block - 1) / block;
        proj_kernel<<<grid, block, 0, stream>>>(positions, pose, intr, Hp, Wp,
                                                winner, (const unsigned*)0,
                                                (unsigned*)0, 0, 0, 0, n, HW);
        int grid2 = (HW + block - 1) / block;
        paint_kernel<<<grid2, block, 0, stream>>>(winner, colors, out, HW);
        return;
    }

    // winner = -1 via vector fill (masks need no init: pass k's read-mask is
    // fully built during pass k-1's dispatch).
    int n4 = HW / 4;
    int fgrid = min((n4 + block - 1) / block, 2048);
    fill_ff_kernel<<<fgrid, block, 0, stream>>>((uint4*)winner, n4);

    // Descending chunks: n/32,n/32,n/16,n/16,n/8,n/8,n/4,5n/16.
    long long ln = n;
    int bounds[9];
    bounds[0] = n;
    bounds[1] = (int)(ln * 31 / 32);
    bounds[2] = (int)(ln * 30 / 32);
    bounds[3] = (int)(ln * 28 / 32);
    bounds[4] = (int)(ln * 26 / 32);
    bounds[5] = (int)(ln * 24 / 32);
    bounds[6] = (int)(ln * 20 / 32);
    bounds[7] = (int)(ln * 10 / 32);
    bounds[8] = 0;
    const int NP = 8;

    for (int k = 0; k < NP; ++k) {
        int end = bounds[k], start = bounds[k + 1];
        if (end <= start) continue;
        const unsigned* mr = (k & 1) ? maskB : maskA;   // built by pass k-1
        unsigned*       mw = (k & 1) ? maskA : maskB;   // for pass k+1
        int build = (k < NP - 1) ? 1 : 0;
        int cnt = end - start;
        int work = max(cnt, build ? HW : 0);
        int grid = min((work + block - 1) / block, 2048);
        proj_kernel<<<grid, block, 0, stream>>>(positions, pose, intr, Hp, Wp,
                                                winner, mr, mw,
                                                (k > 0) ? 1 : 0, build,
                                                start, end, HW);
    }

    int grid2 = (HW + block - 1) / block;
    paint_kernel<<<grid2, block, 0, stream>>>(winner, colors, out, HW);
}